// Round 8
// baseline (82.983 us; speedup 1.0000x reference)
//
#include <hip/hip_runtime.h>
#include <hip/hip_bf16.h>

// ---------------------------------------------------------------------------
// Attention_82961588290112  (B=4, C=64, H=W=64, HW=4096, C8=8)
//
//  out[b,c,q] = sum_k softmax_k(Q^T K)[q,k] * V[c,k]
//             + sum_k softmax_k(Q1^T K1)[q,k] * V[c,k]
//
// R8: ILP push. Residency is pinned at 8 waves/CU (R5/R6/R7: 2 blocks only
// at VGPR<=64, unreachable without spill; 88 and 120 both -> 1 block/CU).
// Counters show ~50% of cycles NEITHER pipe issues (VALU 34%, MFMA 17%):
// latency-chain bound at 2 waves/SIMD. Fix: 2-stage software pipeline per
// wave — QK(next) MFMAs issue before finish(cur)'s exp/pack VALU phase, so
// each wave offers both pipes independent work. VGPR headroom to 256 is
// free (same residency class). V loads moved inside finish (issued before
// exp -> L2 latency hidden under exp work).
// ---------------------------------------------------------------------------

typedef __bf16 bf16x8 __attribute__((ext_vector_type(8)));
typedef float f32x16 __attribute__((ext_vector_type(16)));

#define MFMA32(A, B, C) __builtin_amdgcn_mfma_f32_32x32x16_bf16((A), (B), (C), 0, 0, 0)

#define LOG2E 1.4426950408889634f
#define EXP2F(x) __builtin_amdgcn_exp2f(x)

__device__ __forceinline__ uint4 ld16(const unsigned short* p) {
  return *reinterpret_cast<const uint4*>(p);
}
__device__ __forceinline__ bf16x8 asbf(uint4 v) {
  return __builtin_bit_cast(bf16x8, v);
}
__device__ __forceinline__ unsigned short f2bf(float f) {
  return __builtin_bit_cast(unsigned short, __float2bfloat16(f));
}
__device__ __forceinline__ unsigned pk2(float a, float b) {
  return (unsigned)f2bf(a) | ((unsigned)f2bf(b) << 16);
}

// ---------------------------------------------------------------------------
// Projection kernel: 256 blocks (b * 64 pixel-tiles), 256 threads.
// Q and Q1 outputs are pre-scaled by log2(e) for the exp2 softmax.
// ---------------------------------------------------------------------------
__global__ __launch_bounds__(256) void proj_kernel(
    const float* __restrict__ x, const float* __restrict__ y,
    const float* __restrict__ Wq, const float* __restrict__ bq,
    const float* __restrict__ Wk, const float* __restrict__ bk,
    const float* __restrict__ Wv, const float* __restrict__ bv,
    const float* __restrict__ Wq1, const float* __restrict__ bq1,
    const float* __restrict__ Wk1, const float* __restrict__ bk1,
    unsigned short* __restrict__ Qb, unsigned short* __restrict__ Kb,
    unsigned short* __restrict__ VtT, unsigned short* __restrict__ Q1c,
    unsigned short* __restrict__ K1c)
{
  __shared__ float ldsT[64][64];    // input tile (c, p)
  __shared__ float ldsW[64][65];    // weight, padded
  __shared__ float ldsW2[64][65];   // Wv
  __shared__ float ldsW1[8][64];    // Wq1
  __shared__ float ldsW1b[8][64];   // Wk1

  const int t = threadIdx.x;
  const int b = blockIdx.x >> 6;
  const int p0 = (blockIdx.x & 63) << 6;
  const int lane = t & 63;
  const int w = t >> 6;

  // ---- stage y tile, Wq, Wv, Wq1, Wk1
  for (int i = t; i < 4096; i += 256) {
    int c = i >> 6, p = i & 63;
    ldsT[c][p] = y[(size_t)(b * 64 + c) * 4096 + p0 + p];
    ldsW[c][p] = Wq[i];
    ldsW2[c][p] = Wv[i];
  }
  for (int i = t; i < 512; i += 256) {
    ldsW1[i >> 6][i & 63] = Wq1[i];
    ldsW1b[i >> 6][i & 63] = Wk1[i];
  }
  __syncthreads();

  // ---- Q (oc per lane; wave w handles pixels w*16 .. w*16+15); x log2(e)
  {
    float acc[16];
    float bias = bq[lane];
#pragma unroll
    for (int pp = 0; pp < 16; ++pp) acc[pp] = bias;
    for (int ic = 0; ic < 64; ++ic) {
      float wv_ = ldsW[lane][ic];
#pragma unroll
      for (int pp = 0; pp < 16; ++pp)
        acc[pp] = fmaf(wv_, ldsT[ic][w * 16 + pp], acc[pp]);
    }
#pragma unroll
    for (int pp = 0; pp < 16; ++pp)
      Qb[(size_t)(b * 4096 + p0 + w * 16 + pp) * 64 + lane] = f2bf(acc[pp] * LOG2E);
  }
  __syncthreads();

  // ---- stage x tile, Wk
  for (int i = t; i < 4096; i += 256) {
    int c = i >> 6, p = i & 63;
    ldsT[c][p] = x[(size_t)(b * 64 + c) * 4096 + p0 + p];
    ldsW[c][p] = Wk[i];
  }
  __syncthreads();

  // ---- K (oc per lane)
  {
    float acc[16];
    float bias = bk[lane];
#pragma unroll
    for (int pp = 0; pp < 16; ++pp) acc[pp] = bias;
    for (int ic = 0; ic < 64; ++ic) {
      float wv_ = ldsW[lane][ic];
#pragma unroll
      for (int pp = 0; pp < 16; ++pp)
        acc[pp] = fmaf(wv_, ldsT[ic][w * 16 + pp], acc[pp]);
    }
#pragma unroll
    for (int pp = 0; pp < 16; ++pp)
      Kb[(size_t)(b * 4096 + p0 + w * 16 + pp) * 64 + lane] = f2bf(acc[pp]);
  }

  // ---- V (pixel per lane; wave w handles oc 16w..16w+15)
  //      k-blocked layout: VtT[b][k>>5][c][k&31]
  {
    float acc[16];
#pragma unroll
    for (int j = 0; j < 16; ++j) acc[j] = bv[16 * w + j];
    for (int ic = 0; ic < 64; ++ic) {
      float xv = ldsT[ic][lane];
#pragma unroll
      for (int j = 0; j < 16; ++j)
        acc[j] = fmaf(ldsW2[16 * w + j][ic], xv, acc[j]);
    }
    const int k = p0 + lane;
    const int kblk = k >> 5, ki = k & 31;
#pragma unroll
    for (int j = 0; j < 16; ++j)
      VtT[((size_t)(b * 128 + kblk) * 64 + 16 * w + j) * 32 + ki] = f2bf(acc[j]);
  }

  // ---- Q1 (wave 0, x log2(e)) / K1 (wave 1); pixel per lane, 8 channels
  if (w == 0) {
    float acc[8];
#pragma unroll
    for (int j = 0; j < 8; ++j) acc[j] = bq1[j];
    for (int ic = 0; ic < 64; ++ic) {
      float xv = ldsT[ic][lane];
#pragma unroll
      for (int j = 0; j < 8; ++j)
        acc[j] = fmaf(ldsW1[j][ic], xv, acc[j]);
    }
    uint4 o;
    o.x = pk2(acc[0] * LOG2E, acc[1] * LOG2E);
    o.y = pk2(acc[2] * LOG2E, acc[3] * LOG2E);
    o.z = pk2(acc[4] * LOG2E, acc[5] * LOG2E);
    o.w = pk2(acc[6] * LOG2E, acc[7] * LOG2E);
    *reinterpret_cast<uint4*>(Q1c + (size_t)(b * 4096 + p0 + lane) * 8) = o;
  } else if (w == 1) {
    float acc[8];
#pragma unroll
    for (int j = 0; j < 8; ++j) acc[j] = bk1[j];
    for (int ic = 0; ic < 64; ++ic) {
      float xv = ldsT[ic][lane];
#pragma unroll
      for (int j = 0; j < 8; ++j)
        acc[j] = fmaf(ldsW1b[j][ic], xv, acc[j]);
    }
    uint4 o;
    o.x = pk2(acc[0], acc[1]); o.y = pk2(acc[2], acc[3]);
    o.z = pk2(acc[4], acc[5]); o.w = pk2(acc[6], acc[7]);
    *reinterpret_cast<uint4*>(K1c + (size_t)(b * 4096 + p0 + lane) * 8) = o;
  }
}

// ---------------------------------------------------------------------------
// Fused dual-softmax attention, 32x32 MFMA, in-block split-k=8,
// 2-stage software pipeline (QK of chunk i+1 in flight during finish of i).
// Grid = 512 blocks (4 b x 128 q-tiles) x 512 threads (8 waves).
// ---------------------------------------------------------------------------
__global__ __launch_bounds__(512, 1) void attn_kernel(
    const unsigned short* __restrict__ Qb, const unsigned short* __restrict__ Kb,
    const unsigned short* __restrict__ VtT, const unsigned short* __restrict__ Q1c,
    const unsigned short* __restrict__ K1c, float* __restrict__ out)
{
  __shared__ float accbuf[2][2][64][32];  // [slot][branch][c][q]  32 KB
  __shared__ float zbuf[8][2][32];        // [wave][branch][q]      2 KB

  // XCD-aware decode: id&7 = dispatch XCD; 2 XCDs per batch.
  const int id = blockIdx.x;
  const int b = (id & 7) >> 1;
  const int qt = (id >> 3) + ((id & 1) << 6);   // 0..127
  const int q0 = qt * 32;

  const int wid = threadIdx.x >> 6;   // 0..7
  const int l = threadIdx.x & 63;
  const int qc = l & 31;           // lane's q column (32x32 D: col = lane&31)
  const int h = l >> 5;            // lane half

  const int kBeg = wid << 9;       // in-block split-k: wave owns 512 k

  const f32x16 zero16 = {0.f,0.f,0.f,0.f, 0.f,0.f,0.f,0.f,
                         0.f,0.f,0.f,0.f, 0.f,0.f,0.f,0.f};
  const uint4 zu4 = {0u, 0u, 0u, 0u};

  // ---- hoisted Q fragments (B-operand of S^T): B[c][q], lane slot j -> c=16m+8h+j
  const unsigned short* qrow = Qb + (size_t)(b * 4096 + q0 + qc) * 64 + 8 * h;
  bf16x8 qf[4];
#pragma unroll
  for (int m = 0; m < 4; ++m) qf[m] = asbf(ld16(qrow + 16 * m));
  bf16x8 q1f;
  {
    uint4 v = zu4;
    if (h == 0) v = ld16(Q1c + (size_t)(b * 4096 + q0 + qc) * 8);
    q1f = asbf(v);   // c 8..15 zero
  }

  f32x16 accA0 = zero16, accA1 = zero16, accB0 = zero16, accB1 = zero16;
  float zA = 0.f, zB = 0.f;

  // ---- pipeline helpers (all refs to named vars -> static indexing)
  auto load_k = [&](int k0, uint4* kf, uint4& k1f) {
    const unsigned short* kp = Kb + ((size_t)(b * 4096 + k0 + qc) << 6) + 8 * h;
    kf[0] = ld16(kp);
    kf[1] = ld16(kp + 16);
    kf[2] = ld16(kp + 32);
    kf[3] = ld16(kp + 48);
    k1f = zu4;
    if (h == 0) k1f = ld16(K1c + (size_t)(b * 4096 + k0 + qc) * 8);
  };

  auto qk = [&](const uint4* kf, uint4 k1f, f32x16& sD, f32x16& uD) {
    f32x16 s = MFMA32(asbf(kf[0]), qf[0], zero16);
    s = MFMA32(asbf(kf[1]), qf[1], s);
    s = MFMA32(asbf(kf[2]), qf[2], s);
    s = MFMA32(asbf(kf[3]), qf[3], s);
    sD = s;
    uD = MFMA32(asbf(k1f), q1f, zero16);
  };

  // finish: V loads issued first (latency hidden under exp), then exp2,
  // z-accumulate, pack+permlane relay, PV MFMAs.
  auto finish = [&](int k0, f32x16& sD, f32x16& uD) {
    uint4 vf[4];
    const unsigned short* vp =
        VtT + (((size_t)(b * 128 + (k0 >> 5)) * 64 + qc) << 5) + 8 * h;
    vf[0] = ld16(vp);              // c-tile 0, m=0
    vf[1] = ld16(vp + 16);         // c-tile 0, m=1
    vf[2] = ld16(vp + 32 * 32);    // c-tile 1, m=0
    vf[3] = ld16(vp + 32 * 32 + 16);

    // exp2 in place; reg r -> k-row (r&3)+8*(r>>2)+4h
#pragma unroll
    for (int r = 0; r < 16; ++r) { sD[r] = EXP2F(sD[r]); uD[r] = EXP2F(uD[r]); }
    zA += (((sD[0]+sD[1])+(sD[2]+sD[3])) + ((sD[4]+sD[5])+(sD[6]+sD[7]))) +
          (((sD[8]+sD[9])+(sD[10]+sD[11])) + ((sD[12]+sD[13])+(sD[14]+sD[15])));
    zB += (((uD[0]+uD[1])+(uD[2]+uD[3])) + ((uD[4]+uD[5])+(uD[6]+uD[7]))) +
          (((uD[8]+uD[9])+(uD[10]+uD[11])) + ((uD[12]+uD[13])+(uD[14]+uD[15])));

    // P^T -> PV B-frags: per m (k-half), 4 pk2 + 2 permlane32_swap.
#pragma unroll
    for (int m = 0; m < 2; ++m) {
      unsigned W0 = pk2(sD[8*m+0], sD[8*m+1]);
      unsigned W1 = pk2(sD[8*m+2], sD[8*m+3]);
      unsigned W2 = pk2(sD[8*m+4], sD[8*m+5]);
      unsigned W3 = pk2(sD[8*m+6], sD[8*m+7]);
      auto s1 = __builtin_amdgcn_permlane32_swap((int)W0, (int)W2, false, false);
      auto s2 = __builtin_amdgcn_permlane32_swap((int)W1, (int)W3, false, false);
      uint4 pw;
      pw.x = (unsigned)s1[0]; pw.y = (unsigned)s2[0];
      pw.z = (unsigned)s1[1]; pw.w = (unsigned)s2[1];
      bf16x8 pf = asbf(pw);

      unsigned X0 = pk2(uD[8*m+0], uD[8*m+1]);
      unsigned X1 = pk2(uD[8*m+2], uD[8*m+3]);
      unsigned X2 = pk2(uD[8*m+4], uD[8*m+5]);
      unsigned X3 = pk2(uD[8*m+6], uD[8*m+7]);
      auto t1 = __builtin_amdgcn_permlane32_swap((int)X0, (int)X2, false, false);
      auto t2 = __builtin_amdgcn_permlane32_swap((int)X1, (int)X3, false, false);
      uint4 pw1;
      pw1.x = (unsigned)t1[0]; pw1.y = (unsigned)t2[0];
      pw1.z = (unsigned)t1[1]; pw1.w = (unsigned)t2[1];
      bf16x8 pf1 = asbf(pw1);

      // out^T accumulate: A = V^T (32c x 16k), B = P^T
      accA0 = MFMA32(asbf(vf[m]),     pf,  accA0);
      accA1 = MFMA32(asbf(vf[2 + m]), pf,  accA1);
      accB0 = MFMA32(asbf(vf[m]),     pf1, accB0);
      accB1 = MFMA32(asbf(vf[2 + m]), pf1, accB1);
    }
  };

  // ---- 2-stage pipeline over 16 chunks (8 pairs), explicit A/B state
  uint4 kfA[4], kfB[4], k1fA, k1fB;
  f32x16 sDA, uDA, sDB, uDB;

  load_k(kBeg, kfA, k1fA);
  qk(kfA, k1fA, sDA, uDA);

#pragma unroll 1
  for (int p = 0; p < 8; ++p) {
    const int k0 = kBeg + (p << 6);
    // stage B chunk: loads + QK issue before finish(A)'s VALU phase
    load_k(k0 + 32, kfB, k1fB);
    qk(kfB, k1fB, sDB, uDB);
    finish(k0, sDA, uDA);
    if (p < 7) {
      load_k(k0 + 64, kfA, k1fA);
      qk(kfA, k1fA, sDA, uDA);
    }
    finish(k0 + 32, sDB, uDB);
  }

  // ---- epilogue: h-reduce z, then 3-level LDS tree over 8 waves (2 slots)
  zA += __shfl_xor(zA, 32);
  zB += __shfl_xor(zB, 32);
  if (h == 0) { zbuf[wid][0][qc] = zA; zbuf[wid][1][qc] = zB; }

  auto payload_write = [&](int slot) {
#pragma unroll
    for (int r = 0; r < 16; ++r) {
      const int c0 = (r & 3) + 8 * (r >> 2) + 4 * h;
      accbuf[slot][0][c0][qc]      = accA0[r];
      accbuf[slot][0][c0 + 32][qc] = accA1[r];
      accbuf[slot][1][c0][qc]      = accB0[r];
      accbuf[slot][1][c0 + 32][qc] = accB1[r];
    }
  };
  auto payload_add = [&](int slot) {
#pragma unroll
    for (int r = 0; r < 16; ++r) {
      const int c0 = (r & 3) + 8 * (r >> 2) + 4 * h;
      accA0[r] += accbuf[slot][0][c0][qc];
      accA1[r] += accbuf[slot][0][c0 + 32][qc];
      accB0[r] += accbuf[slot][1][c0][qc];
      accB1[r] += accbuf[slot][1][c0 + 32][qc];
    }
  };

  // pair-reduce 0<-1, 4<-5 (sub-round a), 2<-3, 6<-7 (sub-round b)
  if (wid == 1) payload_write(0);
  if (wid == 5) payload_write(1);
  __syncthreads();
  if (wid == 0) payload_add(0);
  if (wid == 4) payload_add(1);
  __syncthreads();
  if (wid == 3) payload_write(0);
  if (wid == 7) payload_write(1);
  __syncthreads();
  if (wid == 2) payload_add(0);
  if (wid == 6) payload_add(1);
  __syncthreads();
  // quad-reduce 0<-2, 4<-6
  if (wid == 2) payload_write(0);
  if (wid == 6) payload_write(1);
  __syncthreads();
  if (wid == 0) payload_add(0);
  if (wid == 4) payload_add(1);
  __syncthreads();
  // final 0<-4
  if (wid == 4) payload_write(0);
  __syncthreads();
  if (wid == 0) {
    payload_add(0);
    float zAt = 0.f, zBt = 0.f;
#pragma unroll
    for (int ww = 0; ww < 8; ++ww) { zAt += zbuf[ww][0][qc]; zBt += zbuf[ww][1][qc]; }
    const float rA = 1.0f / zAt, rB = 1.0f / zBt;
    float* op = out + (size_t)b * (64 * 4096) + q0 + qc;
#pragma unroll
    for (int r = 0; r < 16; ++r) {
      const int c0 = (r & 3) + 8 * (r >> 2) + 4 * h;
      op[(size_t)c0 * 4096]        = accA0[r] * rA + accB0[r] * rB;
      op[(size_t)(c0 + 32) * 4096] = accA1[r] * rA + accB1[r] * rB;
    }
  }
}

// ---------------------------------------------------------------------------
extern "C" void kernel_launch(void* const* d_in, const int* in_sizes, int n_in,
                              void* d_out, int out_size, void* d_ws, size_t ws_size,
                              hipStream_t stream) {
  (void)in_sizes; (void)n_in; (void)out_size; (void)ws_size;
  const float* x = (const float*)d_in[0];
  const float* y = (const float*)d_in[1];
  const float* Wq = (const float*)d_in[2];
  const float* bq = (const float*)d_in[3];
  const float* Wk = (const float*)d_in[4];
  const float* bk = (const float*)d_in[5];
  const float* Wv = (const float*)d_in[6];
  const float* bv = (const float*)d_in[7];
  const float* Wq1 = (const float*)d_in[8];
  const float* bq1 = (const float*)d_in[9];
  const float* Wk1 = (const float*)d_in[10];
  const float* bk1 = (const float*)d_in[11];

  char* ws = (char*)d_ws;
  unsigned short* Qb = (unsigned short*)(ws);                    // 2 MB
  unsigned short* Kb = (unsigned short*)(ws + (2u << 20));       // 2 MB
  unsigned short* VtT = (unsigned short*)(ws + (4u << 20));      // 2 MB
  unsigned short* Q1c = (unsigned short*)(ws + (6u << 20));      // 256 KB
  unsigned short* K1c = (unsigned short*)(ws + (6u << 20) + (256u << 10)); // 256 KB

  proj_kernel<<<256, 256, 0, stream>>>(x, y, Wq, bq, Wk, bk, Wv, bv,
                                       Wq1, bq1, Wk1, bk1, Qb, Kb, VtT, Q1c, K1c);
  attn_kernel<<<512, 512, 0, stream>>>(Qb, Kb, VtT, Q1c, K1c, (float*)d_out);
}

// Round 9
// 79.481 us; speedup vs baseline: 1.0441x; 1.0441x over previous
//
#include <hip/hip_runtime.h>
#include <hip/hip_bf16.h>

// ---------------------------------------------------------------------------
// Attention_82961588290112  (B=4, C=64, H=W=64, HW=4096, C8=8)
//
//  out[b,c,q] = sum_k softmax_k(Q^T K)[q,k] * V[c,k]
//             + sum_k softmax_k(Q1^T K1)[q,k] * V[c,k]
//
// R9: issue-cost cut. R8 lesson: compiler re-serializes source pipelines
// (VGPR 108, dur flat). Residency accounting fixed: CSV VGPR excludes the
// 64 acc AGPRs; total 152-184 -> 2 waves/SIMD class regardless (m69 steps).
// So cut work per chunk instead:
//   1. pack via hardware v_cvt_pk_bf16_f32 (inline asm) — __float2bfloat16
//      is a ~6-op software RNE sequence; 16 pk2/chunk was ~176 VALU ops.
//   2. s_setprio(1) around MFMA clusters (T5, +4-7% attn measured).
//   3. proj: 32-pixel tiles, 512 blocks -> 2 blocks/CU (was 1) -> ~2x.
// ---------------------------------------------------------------------------

typedef __bf16 bf16x8 __attribute__((ext_vector_type(8)));
typedef float f32x16 __attribute__((ext_vector_type(16)));

#define MFMA32(A, B, C) __builtin_amdgcn_mfma_f32_32x32x16_bf16((A), (B), (C), 0, 0, 0)

#define LOG2E 1.4426950408889634f
#define EXP2F(x) __builtin_amdgcn_exp2f(x)

__device__ __forceinline__ uint4 ld16(const unsigned short* p) {
  return *reinterpret_cast<const uint4*>(p);
}
__device__ __forceinline__ bf16x8 asbf(uint4 v) {
  return __builtin_bit_cast(bf16x8, v);
}
__device__ __forceinline__ unsigned short f2bf(float f) {
  return __builtin_bit_cast(unsigned short, __float2bfloat16(f));
}
// hardware packed f32->bf16 (RNE), lo16 = a, hi16 = b
__device__ __forceinline__ unsigned cvtpk(float a, float b) {
  unsigned r;
  asm("v_cvt_pk_bf16_f32 %0, %1, %2" : "=v"(r) : "v"(a), "v"(b));
  return r;
}

// ---------------------------------------------------------------------------
// Projection kernel: 512 blocks (b * 128 32-pixel tiles), 256 threads.
// Q and Q1 outputs are pre-scaled by log2(e) for the exp2 softmax.
// ---------------------------------------------------------------------------
__global__ __launch_bounds__(256) void proj_kernel(
    const float* __restrict__ x, const float* __restrict__ y,
    const float* __restrict__ Wq, const float* __restrict__ bq,
    const float* __restrict__ Wk, const float* __restrict__ bk,
    const float* __restrict__ Wv, const float* __restrict__ bv,
    const float* __restrict__ Wq1, const float* __restrict__ bq1,
    const float* __restrict__ Wk1, const float* __restrict__ bk1,
    unsigned short* __restrict__ Qb, unsigned short* __restrict__ Kb,
    unsigned short* __restrict__ VtT, unsigned short* __restrict__ Q1c,
    unsigned short* __restrict__ K1c)
{
  __shared__ float ldsT[64][32];    // input tile (c, p)  8 KB
  __shared__ float ldsW[64][65];    // weight, padded     16.6 KB
  __shared__ float ldsW2[64][65];   // Wv                 16.6 KB
  __shared__ float ldsW1[8][64];    // Wq1                 2 KB
  __shared__ float ldsW1b[8][64];   // Wk1                 2 KB

  const int t = threadIdx.x;
  const int b = blockIdx.x >> 7;
  const int p0 = (blockIdx.x & 127) << 5;
  const int lane = t & 63;
  const int w = t >> 6;

  // ---- stage y tile, Wq, Wv, Wq1, Wk1
  for (int i = t; i < 2048; i += 256) {
    int c = i >> 5, p = i & 31;
    ldsT[c][p] = y[(size_t)(b * 64 + c) * 4096 + p0 + p];
  }
  for (int i = t; i < 4096; i += 256) {
    int c = i >> 6, p = i & 63;
    ldsW[c][p] = Wq[i];
    ldsW2[c][p] = Wv[i];
  }
  for (int i = t; i < 512; i += 256) {
    ldsW1[i >> 6][i & 63] = Wq1[i];
    ldsW1b[i >> 6][i & 63] = Wk1[i];
  }
  __syncthreads();

  // ---- Q (oc per lane; wave w handles pixels w*8 .. w*8+7); x log2(e)
  {
    float acc[8];
    float bias = bq[lane];
#pragma unroll
    for (int pp = 0; pp < 8; ++pp) acc[pp] = bias;
    for (int ic = 0; ic < 64; ++ic) {
      float wv_ = ldsW[lane][ic];
#pragma unroll
      for (int pp = 0; pp < 8; ++pp)
        acc[pp] = fmaf(wv_, ldsT[ic][w * 8 + pp], acc[pp]);
    }
#pragma unroll
    for (int pp = 0; pp < 8; ++pp)
      Qb[(size_t)(b * 4096 + p0 + w * 8 + pp) * 64 + lane] = f2bf(acc[pp] * LOG2E);
  }
  __syncthreads();

  // ---- stage x tile, Wk
  for (int i = t; i < 2048; i += 256) {
    int c = i >> 5, p = i & 31;
    ldsT[c][p] = x[(size_t)(b * 64 + c) * 4096 + p0 + p];
  }
  for (int i = t; i < 4096; i += 256) {
    int c = i >> 6, p = i & 63;
    ldsW[c][p] = Wk[i];
  }
  __syncthreads();

  // ---- K (oc per lane)
  {
    float acc[8];
    float bias = bk[lane];
#pragma unroll
    for (int pp = 0; pp < 8; ++pp) acc[pp] = bias;
    for (int ic = 0; ic < 64; ++ic) {
      float wv_ = ldsW[lane][ic];
#pragma unroll
      for (int pp = 0; pp < 8; ++pp)
        acc[pp] = fmaf(wv_, ldsT[ic][w * 8 + pp], acc[pp]);
    }
#pragma unroll
    for (int pp = 0; pp < 8; ++pp)
      Kb[(size_t)(b * 4096 + p0 + w * 8 + pp) * 64 + lane] = f2bf(acc[pp]);
  }

  // ---- V (pixel = lane&31, half = lane>>5; wave w + half -> oc 16w+8*half ..+8)
  //      k-blocked layout: VtT[b][k>>5][c][k&31]
  {
    const int half = lane >> 5;
    const int px = lane & 31;
    const int oc0 = 16 * w + 8 * half;
    float acc[8];
#pragma unroll
    for (int j = 0; j < 8; ++j) acc[j] = bv[oc0 + j];
    for (int ic = 0; ic < 64; ++ic) {
      float xv = ldsT[ic][px];
#pragma unroll
      for (int j = 0; j < 8; ++j)
        acc[j] = fmaf(ldsW2[oc0 + j][ic], xv, acc[j]);
    }
    const int k = p0 + px;
    const int kblk = k >> 5, ki = k & 31;
#pragma unroll
    for (int j = 0; j < 8; ++j)
      VtT[((size_t)(b * 128 + kblk) * 64 + oc0 + j) * 32 + ki] = f2bf(acc[j]);
  }

  // ---- Q1 (wave 0, x log2(e)) / K1 (wave 1); lanes 0..31, pixel per lane
  if (w == 0 && lane < 32) {
    float acc[8];
#pragma unroll
    for (int j = 0; j < 8; ++j) acc[j] = bq1[j];
    for (int ic = 0; ic < 64; ++ic) {
      float xv = ldsT[ic][lane];
#pragma unroll
      for (int j = 0; j < 8; ++j)
        acc[j] = fmaf(ldsW1[j][ic], xv, acc[j]);
    }
    uint4 o;
    o.x = cvtpk(acc[0] * LOG2E, acc[1] * LOG2E);
    o.y = cvtpk(acc[2] * LOG2E, acc[3] * LOG2E);
    o.z = cvtpk(acc[4] * LOG2E, acc[5] * LOG2E);
    o.w = cvtpk(acc[6] * LOG2E, acc[7] * LOG2E);
    *reinterpret_cast<uint4*>(Q1c + (size_t)(b * 4096 + p0 + lane) * 8) = o;
  } else if (w == 1 && lane < 32) {
    float acc[8];
#pragma unroll
    for (int j = 0; j < 8; ++j) acc[j] = bk1[j];
    for (int ic = 0; ic < 64; ++ic) {
      float xv = ldsT[ic][lane];
#pragma unroll
      for (int j = 0; j < 8; ++j)
        acc[j] = fmaf(ldsW1b[j][ic], xv, acc[j]);
    }
    uint4 o;
    o.x = cvtpk(acc[0], acc[1]); o.y = cvtpk(acc[2], acc[3]);
    o.z = cvtpk(acc[4], acc[5]); o.w = cvtpk(acc[6], acc[7]);
    *reinterpret_cast<uint4*>(K1c + (size_t)(b * 4096 + p0 + lane) * 8) = o;
  }
}

// ---------------------------------------------------------------------------
// Fused dual-softmax attention, 32x32 MFMA, in-block split-k=8.
// Grid = 512 blocks (4 b x 128 q-tiles) x 512 threads (8 waves).
// ---------------------------------------------------------------------------
__global__ __launch_bounds__(512, 2) void attn_kernel(
    const unsigned short* __restrict__ Qb, const unsigned short* __restrict__ Kb,
    const unsigned short* __restrict__ VtT, const unsigned short* __restrict__ Q1c,
    const unsigned short* __restrict__ K1c, float* __restrict__ out)
{
  __shared__ float accbuf[2][2][64][32];  // [slot][branch][c][q]  32 KB
  __shared__ float zbuf[8][2][32];        // [wave][branch][q]      2 KB

  // XCD-aware decode: id&7 = dispatch XCD; 2 XCDs per batch.
  const int id = blockIdx.x;
  const int b = (id & 7) >> 1;
  const int qt = (id >> 3) + ((id & 1) << 6);   // 0..127
  const int q0 = qt * 32;

  const int wid = threadIdx.x >> 6;   // 0..7
  const int l = threadIdx.x & 63;
  const int qc = l & 31;           // lane's q column (32x32 D: col = lane&31)
  const int h = l >> 5;            // lane half

  const int kBeg = wid << 9;       // in-block split-k: wave owns 512 k
  const int kEnd = kBeg + 512;

  const f32x16 zero16 = {0.f,0.f,0.f,0.f, 0.f,0.f,0.f,0.f,
                         0.f,0.f,0.f,0.f, 0.f,0.f,0.f,0.f};
  const uint4 zu4 = {0u, 0u, 0u, 0u};

  // ---- hoisted Q fragments (B-operand of S^T): B[c][q], lane slot j -> c=16m+8h+j
  const unsigned short* qrow = Qb + (size_t)(b * 4096 + q0 + qc) * 64 + 8 * h;
  bf16x8 qf[4];
#pragma unroll
  for (int m = 0; m < 4; ++m) qf[m] = asbf(ld16(qrow + 16 * m));
  bf16x8 q1f;
  {
    uint4 v = zu4;
    if (h == 0) v = ld16(Q1c + (size_t)(b * 4096 + q0 + qc) * 8);
    q1f = asbf(v);   // c 8..15 zero
  }

  f32x16 accA0 = zero16, accA1 = zero16, accB0 = zero16, accB1 = zero16;
  float zA = 0.f, zB = 0.f;

#pragma unroll 1
  for (int k0 = kBeg; k0 < kEnd; k0 += 32) {
    // ---- single-buffer staging for this 32-k chunk
    uint4 kf[4], vf[4], k1f;
    {
      const unsigned short* kp = Kb + ((size_t)(b * 4096 + k0 + qc) << 6) + 8 * h;
      kf[0] = ld16(kp);
      kf[1] = ld16(kp + 16);
      kf[2] = ld16(kp + 32);
      kf[3] = ld16(kp + 48);
      k1f = zu4;
      if (h == 0) k1f = ld16(K1c + (size_t)(b * 4096 + k0 + qc) * 8);
      const unsigned short* vp =
          VtT + (((size_t)(b * 128 + (k0 >> 5)) * 64 + qc) << 5) + 8 * h;
      vf[0] = ld16(vp);              // c-tile 0, m=0
      vf[1] = ld16(vp + 16);         // c-tile 0, m=1
      vf[2] = ld16(vp + 32 * 32);    // c-tile 1, m=0
      vf[3] = ld16(vp + 32 * 32 + 16);
    }

    // ---- S^T (32k x 32q): A = K rows, B = Q^T. 4 chained MFMAs over c=64.
    __builtin_amdgcn_s_setprio(1);
    f32x16 sD = MFMA32(asbf(kf[0]), qf[0], zero16);
    sD = MFMA32(asbf(kf[1]), qf[1], sD);
    sD = MFMA32(asbf(kf[2]), qf[2], sD);
    sD = MFMA32(asbf(kf[3]), qf[3], sD);
    f32x16 uD = MFMA32(asbf(k1f), q1f, zero16);
    __builtin_amdgcn_s_setprio(0);

    // ---- exp2 in place (Q pre-scaled by log2 e); reg r -> k-row (r&3)+8*(r>>2)+4h
#pragma unroll
    for (int r = 0; r < 16; ++r) { sD[r] = EXP2F(sD[r]); uD[r] = EXP2F(uD[r]); }
    zA += (((sD[0]+sD[1])+(sD[2]+sD[3])) + ((sD[4]+sD[5])+(sD[6]+sD[7]))) +
          (((sD[8]+sD[9])+(sD[10]+sD[11])) + ((sD[12]+sD[13])+(sD[14]+sD[15])));
    zB += (((uD[0]+uD[1])+(uD[2]+uD[3])) + ((uD[4]+uD[5])+(uD[6]+uD[7]))) +
          (((uD[8]+uD[9])+(uD[10]+uD[11])) + ((uD[12]+uD[13])+(uD[14]+uD[15])));

    // ---- P^T -> PV B-frags: per m (k-half), 4 cvt_pk + 2 permlane32_swap.
#pragma unroll
    for (int m = 0; m < 2; ++m) {
      unsigned W0 = cvtpk(sD[8*m+0], sD[8*m+1]);
      unsigned W1 = cvtpk(sD[8*m+2], sD[8*m+3]);
      unsigned W2 = cvtpk(sD[8*m+4], sD[8*m+5]);
      unsigned W3 = cvtpk(sD[8*m+6], sD[8*m+7]);
      auto s1 = __builtin_amdgcn_permlane32_swap((int)W0, (int)W2, false, false);
      auto s2 = __builtin_amdgcn_permlane32_swap((int)W1, (int)W3, false, false);
      uint4 pw;
      pw.x = (unsigned)s1[0]; pw.y = (unsigned)s2[0];
      pw.z = (unsigned)s1[1]; pw.w = (unsigned)s2[1];
      bf16x8 pf = asbf(pw);

      unsigned X0 = cvtpk(uD[8*m+0], uD[8*m+1]);
      unsigned X1 = cvtpk(uD[8*m+2], uD[8*m+3]);
      unsigned X2 = cvtpk(uD[8*m+4], uD[8*m+5]);
      unsigned X3 = cvtpk(uD[8*m+6], uD[8*m+7]);
      auto t1 = __builtin_amdgcn_permlane32_swap((int)X0, (int)X2, false, false);
      auto t2 = __builtin_amdgcn_permlane32_swap((int)X1, (int)X3, false, false);
      uint4 pw1;
      pw1.x = (unsigned)t1[0]; pw1.y = (unsigned)t2[0];
      pw1.z = (unsigned)t1[1]; pw1.w = (unsigned)t2[1];
      bf16x8 pf1 = asbf(pw1);

      // out^T accumulate: A = V^T (32c x 16k), B = P^T
      __builtin_amdgcn_s_setprio(1);
      accA0 = MFMA32(asbf(vf[m]),     pf,  accA0);
      accA1 = MFMA32(asbf(vf[2 + m]), pf,  accA1);
      accB0 = MFMA32(asbf(vf[m]),     pf1, accB0);
      accB1 = MFMA32(asbf(vf[2 + m]), pf1, accB1);
      __builtin_amdgcn_s_setprio(0);
    }
  }

  // ---- epilogue: h-reduce z, then 3-level LDS tree over 8 waves (2 slots)
  zA += __shfl_xor(zA, 32);
  zB += __shfl_xor(zB, 32);
  if (h == 0) { zbuf[wid][0][qc] = zA; zbuf[wid][1][qc] = zB; }

  auto payload_write = [&](int slot) {
#pragma unroll
    for (int r = 0; r < 16; ++r) {
      const int c0 = (r & 3) + 8 * (r >> 2) + 4 * h;
      accbuf[slot][0][c0][qc]      = accA0[r];
      accbuf[slot][0][c0 + 32][qc] = accA1[r];
      accbuf[slot][1][c0][qc]      = accB0[r];
      accbuf[slot][1][c0 + 32][qc] = accB1[r];
    }
  };
  auto payload_add = [&](int slot) {
#pragma unroll
    for (int r = 0; r < 16; ++r) {
      const int c0 = (r & 3) + 8 * (r >> 2) + 4 * h;
      accA0[r] += accbuf[slot][0][c0][qc];
      accA1[r] += accbuf[slot][0][c0 + 32][qc];
      accB0[r] += accbuf[slot][1][c0][qc];
      accB1[r] += accbuf[slot][1][c0 + 32][qc];
    }
  };

  // pair-reduce 0<-1, 4<-5 (sub-round a), 2<-3, 6<-7 (sub-round b)
  if (wid == 1) payload_write(0);
  if (wid == 5) payload_write(1);
  __syncthreads();
  if (wid == 0) payload_add(0);
  if (wid == 4) payload_add(1);
  __syncthreads();
  if (wid == 3) payload_write(0);
  if (wid == 7) payload_write(1);
  __syncthreads();
  if (wid == 2) payload_add(0);
  if (wid == 6) payload_add(1);
  __syncthreads();
  // quad-reduce 0<-2, 4<-6
  if (wid == 2) payload_write(0);
  if (wid == 6) payload_write(1);
  __syncthreads();
  if (wid == 0) payload_add(0);
  if (wid == 4) payload_add(1);
  __syncthreads();
  // final 0<-4
  if (wid == 4) payload_write(0);
  __syncthreads();
  if (wid == 0) {
    payload_add(0);
    float zAt = 0.f, zBt = 0.f;
#pragma unroll
    for (int ww = 0; ww < 8; ++ww) { zAt += zbuf[ww][0][qc]; zBt += zbuf[ww][1][qc]; }
    const float rA = 1.0f / zAt, rB = 1.0f / zBt;
    float* op = out + (size_t)b * (64 * 4096) + q0 + qc;
#pragma unroll
    for (int r = 0; r < 16; ++r) {
      const int c0 = (r & 3) + 8 * (r >> 2) + 4 * h;
      op[(size_t)c0 * 4096]        = accA0[r] * rA + accB0[r] * rB;
      op[(size_t)(c0 + 32) * 4096] = accA1[r] * rA + accB1[r] * rB;
    }
  }
}

// ---------------------------------------------------------------------------
extern "C" void kernel_launch(void* const* d_in, const int* in_sizes, int n_in,
                              void* d_out, int out_size, void* d_ws, size_t ws_size,
                              hipStream_t stream) {
  (void)in_sizes; (void)n_in; (void)out_size; (void)ws_size;
  const float* x = (const float*)d_in[0];
  const float* y = (const float*)d_in[1];
  const float* Wq = (const float*)d_in[2];
  const float* bq = (const float*)d_in[3];
  const float* Wk = (const float*)d_in[4];
  const float* bk = (const float*)d_in[5];
  const float* Wv = (const float*)d_in[6];
  const float* bv = (const float*)d_in[7];
  const float* Wq1 = (const float*)d_in[8];
  const float* bq1 = (const float*)d_in[9];
  const float* Wk1 = (const float*)d_in[10];
  const float* bk1 = (const float*)d_in[11];

  char* ws = (char*)d_ws;
  unsigned short* Qb = (unsigned short*)(ws);                    // 2 MB
  unsigned short* Kb = (unsigned short*)(ws + (2u << 20));       // 2 MB
  unsigned short* VtT = (unsigned short*)(ws + (4u << 20));      // 2 MB
  unsigned short* Q1c = (unsigned short*)(ws + (6u << 20));      // 256 KB
  unsigned short* K1c = (unsigned short*)(ws + (6u << 20) + (256u << 10)); // 256 KB

  proj_kernel<<<512, 256, 0, stream>>>(x, y, Wq, bq, Wk, bk, Wv, bv,
                                       Wq1, bq1, Wk1, bk1, Qb, Kb, VtT, Q1c, K1c);
  attn_kernel<<<512, 512, 0, stream>>>(Qb, Kb, VtT, Q1c, K1c, (float*)d_out);
}